// Round 5
// baseline (930.131 us; speedup 1.0000x reference)
//
#include <hip/hip_runtime.h>
#include <cstdint>
#include <cstddef>

// ---------------------------------------------------------------------------
// QLoRABigNet: 6 blocks x (linear, relu, linear, relu, linear) + LayerNorm.
// D=1024, BATCH=16384. 4-bit group-quant weights (GS=16), LoRA rank 32 merged
// exactly into dequantized W (W' = W + B@A). 18 bf16 MFMA GEMMs.
// R5 change: pre-LN h goes through bf16 instead of fp32 (GEMM-3 writes bf16,
// LN reads bf16) — saves 64 MB/block of HBM round-trip. Block-5 LN writes
// only the fp32 final output. LN uses 16B loads/stores, 16 elems/lane.
// GEMM untouched: at m97-structure plateau (~780 TF effective, short-K).
// ---------------------------------------------------------------------------

typedef short  bf16x8 __attribute__((ext_vector_type(8)));   // 8 bf16 (4 VGPRs)
typedef float  f32x4  __attribute__((ext_vector_type(4)));

__device__ __forceinline__ unsigned short f2bf(float f) {
  unsigned int u = __builtin_bit_cast(unsigned int, f);
  u += 0x7FFFu + ((u >> 16) & 1u);
  return (unsigned short)(u >> 16);
}

__device__ __forceinline__ float bf2f(unsigned short h) {
  return __builtin_bit_cast(float, (unsigned int)h << 16);
}

__device__ __forceinline__ void async_copy16(void* lds, const void* g) {
  __builtin_amdgcn_global_load_lds(
      (const __attribute__((address_space(1))) void*)(uintptr_t)(g),
      (__attribute__((address_space(3))) void*)(unsigned int)(uintptr_t)(lds),
      16, 0, 0);
}

// ---------------------------------------------------------------------------
// Dequant (+ LoRA merge). 4 independent int4 loads per thread (16 elements),
// all streams coalesced. grid: (256, 18), block 256.
// ---------------------------------------------------------------------------
__global__ __launch_bounds__(256) void dequant_kernel(
    const int* __restrict__ wq, const float* __restrict__ wn,
    const float* __restrict__ lora_a, const float* __restrict__ lora_b,
    unsigned short* __restrict__ Wbf) {
  const int l   = blockIdx.y;
  const int t   = threadIdx.x;
  const int blk = blockIdx.x;
  const long base = (long)l * 1048576;
  const float s = 2.0f / 15.0f;

  int4  q[4];
  float nrm[4];
#pragma unroll
  for (int k = 0; k < 4; ++k) {
    const int i4 = blk * 1024 + k * 256 + t;
    q[k]   = *(const int4*)(wq + base + (long)i4 * 4);
    nrm[k] = wn[l * 65536 + (i4 >> 2)];
  }

  float v[4][4];
#pragma unroll
  for (int k = 0; k < 4; ++k) {
    v[k][0] = ((float)q[k].x * s - 1.0f) * nrm[k];
    v[k][1] = ((float)q[k].y * s - 1.0f) * nrm[k];
    v[k][2] = ((float)q[k].z * s - 1.0f) * nrm[k];
    v[k][3] = ((float)q[k].w * s - 1.0f) * nrm[k];
  }

  const int slot = (l == 0) ? 0 : (l == 6) ? 1 : (l == 12) ? 2 : -1;
  if (slot >= 0) {
    const float* A = lora_a + slot * 32768 + t * 4;      // [32][1024]
    const float* B = lora_b + slot * 32768 + blk * 128;  // rows blk*4..+3
#pragma unroll 8
    for (int r = 0; r < 32; ++r) {
      const float4 a4 = *(const float4*)(A + r * 1024);
#pragma unroll
      for (int k = 0; k < 4; ++k) {
        const float br = B[k * 32 + r];
        v[k][0] = fmaf(br, a4.x, v[k][0]);
        v[k][1] = fmaf(br, a4.y, v[k][1]);
        v[k][2] = fmaf(br, a4.z, v[k][2]);
        v[k][3] = fmaf(br, a4.w, v[k][3]);
      }
    }
  }

#pragma unroll
  for (int k = 0; k < 4; ++k) {
    unsigned short u[4] = {f2bf(v[k][0]), f2bf(v[k][1]),
                           f2bf(v[k][2]), f2bf(v[k][3])};
    const long e0 = base + ((long)blk * 1024 + k * 256 + t) * 4;
    *(uint2*)(Wbf + e0) = *(uint2*)u;
  }
}

// ---------------------------------------------------------------------------
// fp32 -> bf16 for the initial x. 4 independent float4 loads per thread.
// grid 4096, block 256 (16 elems/thread).
// ---------------------------------------------------------------------------
__global__ __launch_bounds__(256) void cvt_bf16_kernel(
    const float* __restrict__ in, unsigned short* __restrict__ out) {
  const long b0 = (long)blockIdx.x * 4096 + threadIdx.x * 4;
  float4 v[4];
#pragma unroll
  for (int k = 0; k < 4; ++k) v[k] = *(const float4*)(in + b0 + k * 1024);
#pragma unroll
  for (int k = 0; k < 4; ++k) {
    unsigned short u[4] = {f2bf(v[k].x), f2bf(v[k].y), f2bf(v[k].z), f2bf(v[k].w)};
    *(ushort4*)(out + b0 + k * 1024) = *(ushort4*)u;
  }
}

// ---------------------------------------------------------------------------
// GEMM: out[m][n] = sum_k H[m][k] * W[n][k] + bias[n]   (bf16 out)
// M=16384, N=1024, K=1024. Tile 128x128, BK=64, 4 waves (2x2), 4x4 MFMA
// 16x16x32 acc/wave, 4 blocks/CU (all 1024 blocks co-resident, zero tail).
// XCD-aware swizzle: all 8 n-tiles of an m-tile on one XCD.
// ---------------------------------------------------------------------------
template <bool RELU>
__global__ __launch_bounds__(256, 4) void gemm_kernel(
    const unsigned short* __restrict__ H,   // [16384][1024] bf16
    const unsigned short* __restrict__ W,   // [1024][1024] bf16 (layer slice)
    const float* __restrict__ bias,         // [1024]
    unsigned short* __restrict__ outb) {
  constexpr int K = 1024;
  constexpr int NN = 1024;

  __shared__ uint4 ldsq[2048];              // 32 KiB: A[0..16K), B[16K..32K)
  char* base = (char*)ldsq;

  const int tid = threadIdx.x;
  const int w   = tid >> 6;
  const int ln  = tid & 63;
  const int b   = blockIdx.x;
  const int m0  = ((b & 7) * 16 + (b >> 6)) * 128;
  const int n0  = ((b >> 3) & 7) * 128;

  // staging: physical chunk P = (w*4+i)*64 + ln; row = P/8; pc = ln&7
  // stored global chunk gc = pc ^ (row&7) = (ln&7) ^ (ln>>3)
  const int gc = (ln & 7) ^ (ln >> 3);
  const unsigned short* gA = H + (size_t)(m0 + w * 32 + (ln >> 3)) * K + gc * 8;
  const unsigned short* gB = W + (size_t)(n0 + w * 32 + (ln >> 3)) * K + gc * 8;
  char* ldsA = base + w * 4096;
  char* ldsB = base + 16384 + w * 4096;

  const int quad = ln >> 4;
  const int lrow = ln & 15;
  const int sw   = lrow & 7;
  const int c0   = ((quad)     ^ sw) * 16;
  const int c1   = ((quad + 4) ^ sw) * 16;
  const int wm   = (w >> 1) * 64;
  const int wn   = (w & 1) * 64;
  const char* fragA = base + (wm + lrow) * 128;
  const char* fragB = base + 16384 + (wn + lrow) * 128;

  f32x4 acc[4][4];
#pragma unroll
  for (int i = 0; i < 4; ++i)
#pragma unroll
    for (int j = 0; j < 4; ++j) acc[i][j] = (f32x4){0.f, 0.f, 0.f, 0.f};

  for (int kt = 0; kt < 16; ++kt) {
    const unsigned short* pA = gA + kt * 64;
    const unsigned short* pB = gB + kt * 64;
#pragma unroll
    for (int i = 0; i < 4; ++i) {
      async_copy16(ldsA + i * 1024, pA + (size_t)i * 8 * K);
      async_copy16(ldsB + i * 1024, pB + (size_t)i * 8 * K);
    }
    __syncthreads();
#pragma unroll
    for (int kk = 0; kk < 2; ++kk) {
      const int co = kk ? c1 : c0;
      bf16x8 af[4], bg[4];
#pragma unroll
      for (int mt = 0; mt < 4; ++mt)
        af[mt] = *(const bf16x8*)(fragA + mt * 2048 + co);
#pragma unroll
      for (int nt = 0; nt < 4; ++nt)
        bg[nt] = *(const bf16x8*)(fragB + nt * 2048 + co);
#pragma unroll
      for (int mt = 0; mt < 4; ++mt)
#pragma unroll
        for (int nt = 0; nt < 4; ++nt)
          acc[mt][nt] = __builtin_amdgcn_mfma_f32_16x16x32_bf16(
              af[mt], bg[nt], acc[mt][nt], 0, 0, 0);
    }
    __syncthreads();
  }

  // epilogue: C/D layout col=lane&15, row=quad*4+reg
#pragma unroll
  for (int nt = 0; nt < 4; ++nt) {
    const int n = n0 + wn + nt * 16 + lrow;
    const float bs = bias[n];
#pragma unroll
    for (int mt = 0; mt < 4; ++mt) {
      const int mb = m0 + wm + mt * 16 + quad * 4;
      f32x4 v = acc[mt][nt];
#pragma unroll
      for (int r = 0; r < 4; ++r) {
        float o = v[r] + bs;
        if (RELU) o = fmaxf(o, 0.0f);
        outb[(size_t)(mb + r) * NN + n] = f2bf(o);
      }
    }
  }
}

// ---------------------------------------------------------------------------
// LayerNorm over rows of 1024, bf16 input. One WAVE per row (4 rows/block),
// 16 elems/lane via 2x16B loads, shuffle-only reduction.
// wf32==0: write bf16 to outb. wf32==1: write fp32 to outf (final block).
// grid 4096, block 256.
// ---------------------------------------------------------------------------
__global__ __launch_bounds__(256) void ln_kernel(
    const unsigned short* __restrict__ in, const float* __restrict__ lnw,
    const float* __restrict__ lnb, unsigned short* __restrict__ outb,
    float* __restrict__ outf, int wf32) {
  const int wv = threadIdx.x >> 6;
  const int ln = threadIdx.x & 63;
  const int row = blockIdx.x * 4 + wv;
  const int col0 = ln * 16;
  const unsigned short* p = in + (size_t)row * 1024 + col0;

  uint4 raw[2];
  raw[0] = *(const uint4*)(p);
  raw[1] = *(const uint4*)(p + 8);
  float v[16];
  const unsigned short* u = (const unsigned short*)raw;
#pragma unroll
  for (int j = 0; j < 16; ++j) v[j] = bf2f(u[j]);

  float s = 0.f, q = 0.f;
#pragma unroll
  for (int j = 0; j < 16; ++j) { s += v[j]; q += v[j] * v[j]; }
#pragma unroll
  for (int off = 32; off; off >>= 1) {
    s += __shfl_xor(s, off);
    q += __shfl_xor(q, off);
  }
  const float mu  = s * (1.0f / 1024.0f);
  const float var = q * (1.0f / 1024.0f) - mu * mu;
  const float rs  = rsqrtf(var + 1e-5f);

  float y[16];
#pragma unroll
  for (int c = 0; c < 4; ++c) {
    const float4 w4 = *(const float4*)(lnw + col0 + c * 4);
    const float4 b4 = *(const float4*)(lnb + col0 + c * 4);
    y[c * 4 + 0] = (v[c * 4 + 0] - mu) * rs * w4.x + b4.x;
    y[c * 4 + 1] = (v[c * 4 + 1] - mu) * rs * w4.y + b4.y;
    y[c * 4 + 2] = (v[c * 4 + 2] - mu) * rs * w4.z + b4.z;
    y[c * 4 + 3] = (v[c * 4 + 3] - mu) * rs * w4.w + b4.w;
  }

  if (!wf32) {
    unsigned short ub[16];
#pragma unroll
    for (int j = 0; j < 16; ++j) ub[j] = f2bf(y[j]);
    uint4* dst = (uint4*)(outb + (size_t)row * 1024 + col0);
    dst[0] = *(uint4*)(ub);
    dst[1] = *(uint4*)(ub + 8);
  } else {
    float* dst = outf + (size_t)row * 1024 + col0;
#pragma unroll
    for (int c = 0; c < 4; ++c)
      *(float4*)(dst + c * 4) = *(const float4*)(y + c * 4);
  }
}

// ---------------------------------------------------------------------------
extern "C" void kernel_launch(void* const* d_in, const int* in_sizes, int n_in,
                              void* d_out, int out_size, void* d_ws, size_t ws_size,
                              hipStream_t stream) {
  const float* x    = (const float*)d_in[0];
  const int*   wq   = (const int*)d_in[1];
  const float* wn   = (const float*)d_in[2];
  const float* bias = (const float*)d_in[3];
  const float* la   = (const float*)d_in[4];
  const float* lb   = (const float*)d_in[5];
  const float* lnw  = (const float*)d_in[6];
  const float* lnb  = (const float*)d_in[7];
  float* out = (float*)d_out;

  char* ws = (char*)d_ws;
  unsigned short* Wbf = (unsigned short*)ws;                         // 37.75 MB
  unsigned short* hA  = (unsigned short*)(ws + 37748736);            // 32 MB
  unsigned short* hB  = (unsigned short*)(ws + 37748736 + 33554432); // 32 MB

  dequant_kernel<<<dim3(256, 18), 256, 0, stream>>>(wq, wn, la, lb, Wbf);
  cvt_bf16_kernel<<<4096, 256, 0, stream>>>(x, hA);

  for (int blk = 0; blk < 6; ++blk) {
    const int l = blk * 3;
    gemm_kernel<true><<<1024, 256, 0, stream>>>(
        hA, Wbf + (size_t)l * 1048576, bias + l * 1024, hB);
    gemm_kernel<true><<<1024, 256, 0, stream>>>(
        hB, Wbf + (size_t)(l + 1) * 1048576, bias + (l + 1) * 1024, hA);
    gemm_kernel<false><<<1024, 256, 0, stream>>>(
        hA, Wbf + (size_t)(l + 2) * 1048576, bias + (l + 2) * 1024, hB);
    ln_kernel<<<4096, 256, 0, stream>>>(
        hB, lnw + blk * 1024, lnb + blk * 1024, hA, out, blk == 5 ? 1 : 0);
  }
}